// Round 6
// baseline (73.741 us; speedup 1.0000x reference)
//
#include <hip/hip_runtime.h>
#include <math.h>

#define BB 64
#define NN 8192
#define TOTAL_W 9356

typedef _Float16 f16x8 __attribute__((ext_vector_type(8)));
typedef float f32x4 __attribute__((ext_vector_type(4)));
typedef float f32x2 __attribute__((ext_vector_type(2)));
typedef unsigned int u32x2 __attribute__((ext_vector_type(2)));

#define L2E 1.44269504088896340736f
#define LN2 0.6931471805599453f

// ---- LDS layout (bytes) ----
#define W0_OFF   0                      // f32 W0r[3][64] row-major (768 B used)
#define FILM_OFF 1024                   // f32 [4 layers][4 prm][64]; prm: 0=bias 1=wsc*L2E 2=bsc*L2E 3=wsh
#define A1_OFF   (FILM_OFF + 4096)      // A-frags L1: [m][t][lane] f16x8 = 8192 B
#define A2_OFF   (A1_OFF + 8192)
#define A3_OFF   (A2_OFF + 8192)        // 2048 B
#define ACT_OFF  (A3_OFF + 2048)        // Act[128 pts][16 x 8B], pair-level XOR swizzle
#define LDS_BYTES (ACT_OFF + 128*128)   // 39936

#define MFMA16(a, b, c) __builtin_amdgcn_mfma_f32_16x16x32_f16(a, b, c, 0, 0, 0)
#define EXP2 __builtin_amdgcn_exp2f
#define LOG2 __builtin_amdgcn_logf
#define RCPF __builtin_amdgcn_rcpf

__device__ __forceinline__ f32x2 pfma(f32x2 a, f32x2 b, f32x2 c) {
  return __builtin_elementwise_fma(a, b, c);
}

__device__ __forceinline__ f32x4 filmq(const unsigned char* smem, int l, int prm, int q) {
  return *(const f32x4*)(smem + FILM_OFF + (((l * 4 + prm) * 64 + q) << 2));
}

// FiLM (+softplus) on a D-quad for one point; returns 2x f16-pairs (8 B).
template<bool SP>
__device__ __forceinline__ u32x2 film_quad(f32x4 acc, float ctx,
                                           f32x4 wscq, f32x4 bscq, f32x4 wshq) {
  f32x2 ctx2 = {ctx, ctx};
  f32x2 one = {1.f, 1.f};
  f32x2 z0 = pfma(ctx2, (f32x2){wscq.x, wscq.y}, (f32x2){bscq.x, bscq.y});
  f32x2 z1 = pfma(ctx2, (f32x2){wscq.z, wscq.w}, (f32x2){bscq.z, bscq.w});
  f32x2 d0 = {EXP2(-z0.x), EXP2(-z0.y)};  d0 += one;
  f32x2 d1 = {EXP2(-z1.x), EXP2(-z1.y)};  d1 += one;
  f32x2 s0 = {RCPF(d0.x), RCPF(d0.y)};
  f32x2 s1 = {RCPF(d1.x), RCPF(d1.y)};
  f32x2 v0 = pfma(ctx2, (f32x2){wshq.x, wshq.y}, s0 * (f32x2){acc.x, acc.y});
  f32x2 v1 = pfma(ctx2, (f32x2){wshq.z, wshq.w}, s1 * (f32x2){acc.z, acc.w});
  if (SP) {  // softplus = LN2 * log2(1 + 2^(v*L2E))
    f32x2 l2 = {L2E, L2E}, ln = {LN2, LN2};
    f32x2 t0 = v0 * l2, t1 = v1 * l2;
    f32x2 u0 = {EXP2(t0.x), EXP2(t0.y)};  u0 += one;
    f32x2 u1 = {EXP2(t1.x), EXP2(t1.y)};  u1 += one;
    f32x2 g0 = {LOG2(u0.x), LOG2(u0.y)};
    f32x2 g1 = {LOG2(u1.x), LOG2(u1.y)};
    v0 = g0 * ln;
    v1 = g1 * ln;
  }
  auto p01 = __builtin_amdgcn_cvt_pkrtz(v0.x, v0.y);
  auto p23 = __builtin_amdgcn_cvt_pkrtz(v1.x, v1.y);
  u32x2 w;
  w.x = __builtin_bit_cast(unsigned int, p01);
  w.y = __builtin_bit_cast(unsigned int, p23);
  return w;
}

// slot s (4 feats each) stored at 8B-pos ((s>>1)^(pt&7))*2 | (s&1)
__device__ __forceinline__ void act_store(unsigned char* smem, int pt, int slot, u32x2 w) {
  int pos = ((((slot >> 1) ^ (pt & 7)) << 1) | (slot & 1));
  *(u32x2*)(smem + ACT_OFF + pt * 128 + (pos << 3)) = w;
}
// read 16B granule 'pair' (slots 2p,2p+1 = feats 8p..8p+7)
__device__ __forceinline__ f16x8 act_load(const unsigned char* smem, int pt, int pair) {
  int gr = pair ^ (pt & 7);
  return *(const f16x8*)(smem + ACT_OFF + pt * 128 + (gr << 4));
}

__device__ __forceinline__ void process_half(
    unsigned char* smem,
    const f16x8 (&A1r)[4][2], const f16x8 (&A2r)[4][2], const f16x8 (&A3r)[2],
    float ctx0, float ctx1,
    float y00, float y01, float y02, float y10, float y11, float y12,
    int pt0, int pt1, int g, int q4, int n0, int n1, int b,
    float* __restrict__ out) {
  // ----- layer 0 (3 -> 64), packed VALU, bias folded into acc init -----
#pragma unroll
  for (int m = 0; m < 4; ++m) {
    const int q = 16 * m + q4;
    f32x4 biasq = filmq(smem, 0, 0, q);
    f32x4 w0a = *(const f32x4*)(smem + W0_OFF + ((0 * 64 + q) << 2));
    f32x4 w0b = *(const f32x4*)(smem + W0_OFF + ((1 * 64 + q) << 2));
    f32x4 w0c = *(const f32x4*)(smem + W0_OFF + ((2 * 64 + q) << 2));
    f32x2 aLo, aHi, cLo, cHi;
    aLo = pfma((f32x2){y00, y00}, (f32x2){w0a.x, w0a.y}, (f32x2){biasq.x, biasq.y});
    aLo = pfma((f32x2){y01, y01}, (f32x2){w0b.x, w0b.y}, aLo);
    aLo = pfma((f32x2){y02, y02}, (f32x2){w0c.x, w0c.y}, aLo);
    aHi = pfma((f32x2){y00, y00}, (f32x2){w0a.z, w0a.w}, (f32x2){biasq.z, biasq.w});
    aHi = pfma((f32x2){y01, y01}, (f32x2){w0b.z, w0b.w}, aHi);
    aHi = pfma((f32x2){y02, y02}, (f32x2){w0c.z, w0c.w}, aHi);
    cLo = pfma((f32x2){y10, y10}, (f32x2){w0a.x, w0a.y}, (f32x2){biasq.x, biasq.y});
    cLo = pfma((f32x2){y11, y11}, (f32x2){w0b.x, w0b.y}, cLo);
    cLo = pfma((f32x2){y12, y12}, (f32x2){w0c.x, w0c.y}, cLo);
    cHi = pfma((f32x2){y10, y10}, (f32x2){w0a.z, w0a.w}, (f32x2){biasq.z, biasq.w});
    cHi = pfma((f32x2){y11, y11}, (f32x2){w0b.z, w0b.w}, cHi);
    cHi = pfma((f32x2){y12, y12}, (f32x2){w0c.z, w0c.w}, cHi);
    f32x4 acc0 = {aLo.x, aLo.y, aHi.x, aHi.y};
    f32x4 acc1 = {cLo.x, cLo.y, cHi.x, cHi.y};
    f32x4 wscq = filmq(smem, 0, 1, q);
    f32x4 bscq = filmq(smem, 0, 2, q);
    f32x4 wshq = filmq(smem, 0, 3, q);
    act_store(smem, pt0, 4 * m + g, film_quad<true>(acc0, ctx0, wscq, bscq, wshq));
    act_store(smem, pt1, 4 * m + g, film_quad<true>(acc1, ctx1, wscq, bscq, wshq));
  }

  // ----- layers 1,2 (64 -> 64) on MFMA, A-operands from registers -----
#pragma unroll
  for (int L = 1; L <= 2; ++L) {
    f16x8 B00 = act_load(smem, pt0, g);
    f16x8 B01 = act_load(smem, pt0, 4 + g);
    f16x8 B10 = act_load(smem, pt1, g);
    f16x8 B11 = act_load(smem, pt1, 4 + g);
#pragma unroll
    for (int m = 0; m < 4; ++m) {
      const int q = 16 * m + q4;
      f32x4 biasq = filmq(smem, L, 0, q);
      f16x8 a0 = (L == 1) ? A1r[m][0] : A2r[m][0];
      f16x8 a1 = (L == 1) ? A1r[m][1] : A2r[m][1];
      f32x4 c0 = biasq, c1 = biasq;
      c0 = MFMA16(a0, B00, c0);
      c0 = MFMA16(a1, B01, c0);
      c1 = MFMA16(a0, B10, c1);
      c1 = MFMA16(a1, B11, c1);
      f32x4 wscq = filmq(smem, L, 1, q);
      f32x4 bscq = filmq(smem, L, 2, q);
      f32x4 wshq = filmq(smem, L, 3, q);
      act_store(smem, pt0, 4 * m + g, film_quad<true>(c0, ctx0, wscq, bscq, wshq));
      act_store(smem, pt1, 4 * m + g, film_quad<true>(c1, ctx1, wscq, bscq, wshq));
    }
  }

  // ----- layer 3 (64 -> 3) on MFMA, FiLM only -----
  {
    f16x8 B00 = act_load(smem, pt0, g);
    f16x8 B01 = act_load(smem, pt0, 4 + g);
    f16x8 B10 = act_load(smem, pt1, g);
    f16x8 B11 = act_load(smem, pt1, 4 + g);
    f32x4 biasq = filmq(smem, 3, 0, q4);  // zeros beyond feat 2 (staged)
    f32x4 c0 = biasq, c1 = biasq;
    c0 = MFMA16(A3r[0], B00, c0);
    c0 = MFMA16(A3r[1], B01, c0);
    c1 = MFMA16(A3r[0], B10, c1);
    c1 = MFMA16(A3r[1], B11, c1);
    f32x4 wscq = filmq(smem, 3, 1, q4);
    f32x4 bscq = filmq(smem, 3, 2, q4);
    f32x4 wshq = filmq(smem, 3, 3, q4);
    if (g == 0) {
#pragma unroll
      for (int p = 0; p < 2; ++p) {
        f32x4 c = p ? c1 : c0;
        float ctx = p ? ctx1 : ctx0;
        int n = p ? n1 : n0;
#pragma unroll
        for (int j = 0; j < 3; ++j) {
          float z = fmaf(ctx, wscq[j], bscq[j]);
          float s = RCPF(1.0f + EXP2(-z));
          float v = fmaf(ctx, wshq[j], s * c[j]);
          out[((size_t)b * NN + n) * 3 + j] = v;
        }
      }
    }
  }
}

__global__ __launch_bounds__(256, 4)
void ode_hypernet_kernel(const float* __restrict__ context,
                         const float* __restrict__ y,
                         const float* __restrict__ tnw,
                         float* __restrict__ out) {
  __shared__ __align__(16) unsigned char smem[LDS_BYTES];
  const int b = blockIdx.y;
  const int tid = threadIdx.x;
  const float* __restrict__ wb = tnw + (size_t)b * TOTAL_W;

  // ---------- staging ----------
  if (tid < 192) ((float*)(smem + W0_OFF))[tid] = wb[tid];  // W0 rows 3x64
  if (tid < 64) {
    const int biaso[4] = {192, 4544, 8896, 9344};
    const int dim[4] = {64, 64, 64, 3};
#pragma unroll
    for (int l = 0; l < 4; ++l) {
      float bv = 0.f, wscv = 0.f, bscv = 0.f, wshv = 0.f;
      if (tid < dim[l]) {
        int bo = biaso[l], d = dim[l];
        bv = wb[bo + tid];
        wscv = wb[bo + d + tid] * L2E;
        bscv = wb[bo + 2 * d + tid] * L2E;
        wshv = wb[bo + 3 * d + tid];
      }
      float* f = (float*)(smem + FILM_OFF) + l * 256;
      f[tid] = bv;
      f[64 + tid] = wscv;
      f[128 + tid] = bscv;
      f[192 + tid] = wshv;
    }
  }
  // A-fragments L1/L2 (A = W^T, 16x32 tiles)
#pragma unroll
  for (int L = 0; L < 2; ++L) {
    const int woff = L ? 4800 : 448;
    const int aoff = L ? A2_OFF : A1_OFF;
    for (int r = tid; r < 512; r += 256) {
      int lane_r = r & 63;
      int t = (r >> 6) & 1;
      int m = r >> 7;
      int f_out = 16 * m + (lane_r & 15);
      int f_in0 = 32 * t + 8 * (lane_r >> 4);
      f16x8 h;
#pragma unroll
      for (int i = 0; i < 8; ++i) h[i] = (_Float16)wb[woff + (f_in0 + i) * 64 + f_out];
      *(f16x8*)(smem + aoff + r * 16) = h;
    }
  }
  if (tid < 128) {  // A3: W3[f_in][3], rows>=3 zero
    int lane_r = tid & 63;
    int t = tid >> 6;
    int f_out = lane_r & 15;
    int f_in0 = 32 * t + 8 * (lane_r >> 4);
    f16x8 h;
#pragma unroll
    for (int i = 0; i < 8; ++i)
      h[i] = (f_out < 3) ? (_Float16)wb[9152 + (f_in0 + i) * 3 + f_out] : (_Float16)0.f;
    *(f16x8*)(smem + A3_OFF + tid * 16) = h;
  }
  __syncthreads();

  // ---------- hoist A-fragments into registers (shared by both halves) ----------
  const int lane = tid & 63;
  f16x8 A1r[4][2], A2r[4][2], A3r[2];
#pragma unroll
  for (int m = 0; m < 4; ++m) {
#pragma unroll
    for (int t = 0; t < 2; ++t) {
      A1r[m][t] = *(const f16x8*)(smem + A1_OFF + ((m * 2 + t) * 64 + lane) * 16);
      A2r[m][t] = *(const f16x8*)(smem + A2_OFF + ((m * 2 + t) * 64 + lane) * 16);
    }
  }
  A3r[0] = *(const f16x8*)(smem + A3_OFF + (0 * 64 + lane) * 16);
  A3r[1] = *(const f16x8*)(smem + A3_OFF + (1 * 64 + lane) * 16);

  // ---------- per-wave main ----------
  const int wid = tid >> 6;
  const int g = lane >> 4;
  const int col = lane & 15;
  const int pt0 = wid * 32 + col;
  const int pt1 = pt0 + 16;
  const int q4 = 4 * g;

  // preload both halves' inputs
  const int nb = blockIdx.x * 256;
  const int nA0 = nb + pt0, nA1 = nb + pt1;
  const int nB0 = nb + 128 + pt0, nB1 = nb + 128 + pt1;
  const size_t cb = (size_t)b * NN;
  const float cA0 = context[cb + nA0], cA1 = context[cb + nA1];
  const float cB0 = context[cb + nB0], cB1 = context[cb + nB1];
  const float* yA0p = y + (cb + nA0) * 3;
  const float* yA1p = y + (cb + nA1) * 3;
  const float* yB0p = y + (cb + nB0) * 3;
  const float* yB1p = y + (cb + nB1) * 3;
  const float yA00 = yA0p[0], yA01 = yA0p[1], yA02 = yA0p[2];
  const float yA10 = yA1p[0], yA11 = yA1p[1], yA12 = yA1p[2];
  const float yB00 = yB0p[0], yB01 = yB0p[1], yB02 = yB0p[2];
  const float yB10 = yB1p[0], yB11 = yB1p[1], yB12 = yB1p[2];

  process_half(smem, A1r, A2r, A3r, cA0, cA1,
               yA00, yA01, yA02, yA10, yA11, yA12,
               pt0, pt1, g, q4, nA0, nA1, b, out);
  process_half(smem, A1r, A2r, A3r, cB0, cB1,
               yB00, yB01, yB02, yB10, yB11, yB12,
               pt0, pt1, g, q4, nB0, nB1, b, out);
}

extern "C" void kernel_launch(void* const* d_in, const int* in_sizes, int n_in,
                              void* d_out, int out_size, void* d_ws, size_t ws_size,
                              hipStream_t stream) {
  const float* context = (const float*)d_in[0];  // (64, 8192)
  const float* y       = (const float*)d_in[1];  // (64, 8192, 3)
  const float* tnw     = (const float*)d_in[2];  // (64, 9356)
  float* out           = (float*)d_out;          // (64, 8192, 3)

  dim3 grid(NN / 256, BB, 1);  // 2048 blocks, 256 points each (2 halves x 128)
  dim3 block(256, 1, 1);
  ode_hypernet_kernel<<<grid, block, 0, stream>>>(context, y, tnw, out);
}

// Round 7
// 53.278 us; speedup vs baseline: 1.3841x; 1.3841x over previous
//
#include <hip/hip_runtime.h>
#include <math.h>

#define BB 64
#define NN 8192
#define TOTAL_W 9356

typedef _Float16 f16x8 __attribute__((ext_vector_type(8)));
typedef float f32x4 __attribute__((ext_vector_type(4)));
typedef float f32x2 __attribute__((ext_vector_type(2)));
typedef unsigned int u32x2 __attribute__((ext_vector_type(2)));

#define L2E 1.44269504088896340736f
#define LN2 0.6931471805599453f

// ---- LDS layout (bytes) ----
#define W0_OFF   0                      // f32 W0r[3][64] row-major (768 B)
#define FILM_OFF 768                    // f32 [4 layers][4 prm][64]; prm: 0=bias 1=wsc*L2E 2=bsc*L2E 3=wsh (4096 B)
#define A1_OFF   (FILM_OFF + 4096)     // A-frags L1: [m][t][lane] f16x8 = 8192 B
#define A2_OFF   (A1_OFF + 8192)       // A-frags L2: 8192 B
#define ACT_OFF  (A2_OFF + 8192)       // Act[256 pts][16 x 8B], pair-level XOR swizzle = 32768 B
#define LDS_BYTES (ACT_OFF + 256*128)  // 54016 -> 3 blocks/CU (3*54016 = 162048 <= 163840)

#define MFMA16(a, b, c) __builtin_amdgcn_mfma_f32_16x16x32_f16(a, b, c, 0, 0, 0)
#define EXP2 __builtin_amdgcn_exp2f
#define LOG2 __builtin_amdgcn_logf
#define RCPF __builtin_amdgcn_rcpf

__device__ __forceinline__ f32x2 pfma(f32x2 a, f32x2 b, f32x2 c) {
  return __builtin_elementwise_fma(a, b, c);
}

__device__ __forceinline__ f32x4 filmq(const unsigned char* smem, int l, int prm, int q) {
  return *(const f32x4*)(smem + FILM_OFF + (((l * 4 + prm) * 64 + q) << 2));
}

// FiLM (+softplus) on a D-quad for one point; returns 2x f16-pairs (8 B).
template<bool SP>
__device__ __forceinline__ u32x2 film_quad(f32x4 acc, float ctx,
                                           f32x4 wscq, f32x4 bscq, f32x4 wshq) {
  f32x2 ctx2 = {ctx, ctx};
  f32x2 one = {1.f, 1.f};
  f32x2 z0 = pfma(ctx2, (f32x2){wscq.x, wscq.y}, (f32x2){bscq.x, bscq.y});
  f32x2 z1 = pfma(ctx2, (f32x2){wscq.z, wscq.w}, (f32x2){bscq.z, bscq.w});
  f32x2 d0 = {EXP2(-z0.x), EXP2(-z0.y)};  d0 += one;
  f32x2 d1 = {EXP2(-z1.x), EXP2(-z1.y)};  d1 += one;
  f32x2 s0 = {RCPF(d0.x), RCPF(d0.y)};
  f32x2 s1 = {RCPF(d1.x), RCPF(d1.y)};
  f32x2 v0 = pfma(ctx2, (f32x2){wshq.x, wshq.y}, s0 * (f32x2){acc.x, acc.y});
  f32x2 v1 = pfma(ctx2, (f32x2){wshq.z, wshq.w}, s1 * (f32x2){acc.z, acc.w});
  if (SP) {  // softplus = LN2 * log2(1 + 2^(v*L2E))
    f32x2 l2 = {L2E, L2E}, ln = {LN2, LN2};
    f32x2 t0 = v0 * l2, t1 = v1 * l2;
    f32x2 u0 = {EXP2(t0.x), EXP2(t0.y)};  u0 += one;
    f32x2 u1 = {EXP2(t1.x), EXP2(t1.y)};  u1 += one;
    f32x2 g0 = {LOG2(u0.x), LOG2(u0.y)};
    f32x2 g1 = {LOG2(u1.x), LOG2(u1.y)};
    v0 = g0 * ln;
    v1 = g1 * ln;
  }
  auto p01 = __builtin_amdgcn_cvt_pkrtz(v0.x, v0.y);
  auto p23 = __builtin_amdgcn_cvt_pkrtz(v1.x, v1.y);
  u32x2 w;
  w.x = __builtin_bit_cast(unsigned int, p01);
  w.y = __builtin_bit_cast(unsigned int, p23);
  return w;
}

// slot s (4 feats each) stored at 8B-pos ((s>>1)^(pt&7))*2 | (s&1)
__device__ __forceinline__ void act_store(unsigned char* smem, int pt, int slot, u32x2 w) {
  int pos = ((((slot >> 1) ^ (pt & 7)) << 1) | (slot & 1));
  *(u32x2*)(smem + ACT_OFF + pt * 128 + (pos << 3)) = w;
}
// read 16B granule 'pair' (slots 2p,2p+1 = feats 8p..8p+7)
__device__ __forceinline__ f16x8 act_load(const unsigned char* smem, int pt, int pair) {
  int gr = pair ^ (pt & 7);
  return *(const f16x8*)(smem + ACT_OFF + pt * 128 + (gr << 4));
}

__global__ __launch_bounds__(512, 6)
void ode_hypernet_kernel(const float* __restrict__ context,
                         const float* __restrict__ y,
                         const float* __restrict__ tnw,
                         float* __restrict__ out) {
  __shared__ __align__(16) unsigned char smem[LDS_BYTES];
  const int b = blockIdx.y;
  const int tid = threadIdx.x;
  const float* __restrict__ wb = tnw + (size_t)b * TOTAL_W;

  // ---------- staging (512 threads) ----------
  if (tid < 192) ((float*)(smem + W0_OFF))[tid] = wb[tid];  // W0 rows 3x64
  if (tid < 64) {
    const int biaso[4] = {192, 4544, 8896, 9344};
    const int dim[4] = {64, 64, 64, 3};
#pragma unroll
    for (int l = 0; l < 4; ++l) {
      float bv = 0.f, wscv = 0.f, bscv = 0.f, wshv = 0.f;
      if (tid < dim[l]) {
        int bo = biaso[l], d = dim[l];
        bv = wb[bo + tid];
        wscv = wb[bo + d + tid] * L2E;
        bscv = wb[bo + 2 * d + tid] * L2E;
        wshv = wb[bo + 3 * d + tid];
      }
      float* f = (float*)(smem + FILM_OFF) + l * 256;
      f[tid] = bv;
      f[64 + tid] = wscv;
      f[128 + tid] = bscv;
      f[192 + tid] = wshv;
    }
  }
  // A-fragments L1/L2: vectorized gather. Element (f_in, f_out) lives at
  // aoff + (m*128 + t*64 + h*16 + c)*16 + i*2, with m=f_out>>4, c=f_out&15,
  // t=f_in>>5, h=(f_in>>3)&3, i=f_in&7.
#pragma unroll
  for (int L = 0; L < 2; ++L) {
    const int woff = L ? 4800 : 448;
    const int aoff = L ? A2_OFF : A1_OFF;
#pragma unroll
    for (int it = 0; it < 2; ++it) {
      int idx = tid + it * 512;            // 1024 = 64 f_in x 16 quads
      int f_in = idx >> 4;
      int q = idx & 15;
      f32x4 w4 = *(const f32x4*)(wb + woff + f_in * 64 + q * 4);
      int m = q >> 2;
      int c4 = (q & 3) * 4;
      int t = f_in >> 5;
      int h = (f_in >> 3) & 3;
      int i = f_in & 7;
      unsigned char* base = smem + aoff + (m * 128 + t * 64 + h * 16 + c4) * 16 + i * 2;
#pragma unroll
      for (int j = 0; j < 4; ++j)
        *(_Float16*)(base + j * 16) = (_Float16)w4[j];
    }
  }
  // A3 fragments: per-wave registers straight from global (no LDS).
  const int lane = tid & 63;
  const int colA = lane & 15;
  const int hA = lane >> 4;
  f16x8 A3r0, A3r1;
#pragma unroll
  for (int i = 0; i < 8; ++i) {
    A3r0[i] = (colA < 3) ? (_Float16)wb[9152 + (8 * hA + i) * 3 + colA] : (_Float16)0.f;
    A3r1[i] = (colA < 3) ? (_Float16)wb[9152 + (32 + 8 * hA + i) * 3 + colA] : (_Float16)0.f;
  }
  __syncthreads();

  // ---------- per-wave main ----------
  const int wid = tid >> 6;          // 0..7
  const int g = lane >> 4;
  const int col = lane & 15;
  const int pt0 = wid * 32 + col;    // 0..255
  const int pt1 = pt0 + 16;
  const int q4 = 4 * g;

#pragma unroll 1
  for (int ss = 0; ss < 2; ++ss) {
    const int nbase = blockIdx.x * 512 + ss * 256;
    const int n0 = nbase + pt0, n1 = nbase + pt1;
    const float ctx0 = context[(size_t)b * NN + n0];
    const float ctx1 = context[(size_t)b * NN + n1];
    const size_t yb0 = ((size_t)b * NN + n0) * 3;
    const size_t yb1 = ((size_t)b * NN + n1) * 3;
    const float y00 = y[yb0], y01 = y[yb0 + 1], y02 = y[yb0 + 2];
    const float y10 = y[yb1], y11 = y[yb1 + 1], y12 = y[yb1 + 2];

    // ----- layer 0 (3 -> 64), packed VALU, bias folded into acc init -----
#pragma unroll
    for (int m = 0; m < 4; ++m) {
      const int q = 16 * m + q4;
      f32x4 biasq = filmq(smem, 0, 0, q);
      f32x4 w0a = *(const f32x4*)(smem + W0_OFF + ((0 * 64 + q) << 2));
      f32x4 w0b = *(const f32x4*)(smem + W0_OFF + ((1 * 64 + q) << 2));
      f32x4 w0c = *(const f32x4*)(smem + W0_OFF + ((2 * 64 + q) << 2));
      f32x2 aLo, aHi, cLo, cHi;
      aLo = pfma((f32x2){y00, y00}, (f32x2){w0a.x, w0a.y}, (f32x2){biasq.x, biasq.y});
      aLo = pfma((f32x2){y01, y01}, (f32x2){w0b.x, w0b.y}, aLo);
      aLo = pfma((f32x2){y02, y02}, (f32x2){w0c.x, w0c.y}, aLo);
      aHi = pfma((f32x2){y00, y00}, (f32x2){w0a.z, w0a.w}, (f32x2){biasq.z, biasq.w});
      aHi = pfma((f32x2){y01, y01}, (f32x2){w0b.z, w0b.w}, aHi);
      aHi = pfma((f32x2){y02, y02}, (f32x2){w0c.z, w0c.w}, aHi);
      cLo = pfma((f32x2){y10, y10}, (f32x2){w0a.x, w0a.y}, (f32x2){biasq.x, biasq.y});
      cLo = pfma((f32x2){y11, y11}, (f32x2){w0b.x, w0b.y}, cLo);
      cLo = pfma((f32x2){y12, y12}, (f32x2){w0c.x, w0c.y}, cLo);
      cHi = pfma((f32x2){y10, y10}, (f32x2){w0a.z, w0a.w}, (f32x2){biasq.z, biasq.w});
      cHi = pfma((f32x2){y11, y11}, (f32x2){w0b.z, w0b.w}, cHi);
      cHi = pfma((f32x2){y12, y12}, (f32x2){w0c.z, w0c.w}, cHi);
      f32x4 acc0 = {aLo.x, aLo.y, aHi.x, aHi.y};
      f32x4 acc1 = {cLo.x, cLo.y, cHi.x, cHi.y};
      f32x4 wscq = filmq(smem, 0, 1, q);
      f32x4 bscq = filmq(smem, 0, 2, q);
      f32x4 wshq = filmq(smem, 0, 3, q);
      act_store(smem, pt0, 4 * m + g, film_quad<true>(acc0, ctx0, wscq, bscq, wshq));
      act_store(smem, pt1, 4 * m + g, film_quad<true>(acc1, ctx1, wscq, bscq, wshq));
    }

    // ----- layers 1,2 (64 -> 64) on MFMA -----
#pragma unroll
    for (int L = 1; L <= 2; ++L) {
      const int aoff = (L == 1) ? A1_OFF : A2_OFF;
      f16x8 B00 = act_load(smem, pt0, g);
      f16x8 B01 = act_load(smem, pt0, 4 + g);
      f16x8 B10 = act_load(smem, pt1, g);
      f16x8 B11 = act_load(smem, pt1, 4 + g);
#pragma unroll
      for (int m = 0; m < 4; ++m) {
        const int q = 16 * m + q4;
        f32x4 biasq = filmq(smem, L, 0, q);
        f16x8 a0 = *(const f16x8*)(smem + aoff + ((m * 2 + 0) * 64 + lane) * 16);
        f16x8 a1 = *(const f16x8*)(smem + aoff + ((m * 2 + 1) * 64 + lane) * 16);
        f32x4 c0 = biasq, c1 = biasq;
        c0 = MFMA16(a0, B00, c0);
        c0 = MFMA16(a1, B01, c0);
        c1 = MFMA16(a0, B10, c1);
        c1 = MFMA16(a1, B11, c1);
        f32x4 wscq = filmq(smem, L, 1, q);
        f32x4 bscq = filmq(smem, L, 2, q);
        f32x4 wshq = filmq(smem, L, 3, q);
        act_store(smem, pt0, 4 * m + g, film_quad<true>(c0, ctx0, wscq, bscq, wshq));
        act_store(smem, pt1, 4 * m + g, film_quad<true>(c1, ctx1, wscq, bscq, wshq));
      }
    }

    // ----- layer 3 (64 -> 3) on MFMA (A from regs), FiLM only -----
    {
      f16x8 B00 = act_load(smem, pt0, g);
      f16x8 B01 = act_load(smem, pt0, 4 + g);
      f16x8 B10 = act_load(smem, pt1, g);
      f16x8 B11 = act_load(smem, pt1, 4 + g);
      f32x4 biasq = filmq(smem, 3, 0, q4);  // zeros beyond feat 2 (staged)
      f32x4 c0 = biasq, c1 = biasq;
      c0 = MFMA16(A3r0, B00, c0);
      c0 = MFMA16(A3r1, B01, c0);
      c1 = MFMA16(A3r0, B10, c1);
      c1 = MFMA16(A3r1, B11, c1);
      f32x4 wscq = filmq(smem, 3, 1, q4);
      f32x4 bscq = filmq(smem, 3, 2, q4);
      f32x4 wshq = filmq(smem, 3, 3, q4);
      if (g == 0) {
#pragma unroll
        for (int p = 0; p < 2; ++p) {
          f32x4 c = p ? c1 : c0;
          float ctx = p ? ctx1 : ctx0;
          int n = p ? n1 : n0;
#pragma unroll
          for (int j = 0; j < 3; ++j) {
            float z = fmaf(ctx, wscq[j], bscq[j]);
            float s = RCPF(1.0f + EXP2(-z));
            float v = fmaf(ctx, wshq[j], s * c[j]);
            out[((size_t)b * NN + n) * 3 + j] = v;
          }
        }
      }
    }
  }
}

extern "C" void kernel_launch(void* const* d_in, const int* in_sizes, int n_in,
                              void* d_out, int out_size, void* d_ws, size_t ws_size,
                              hipStream_t stream) {
  const float* context = (const float*)d_in[0];  // (64, 8192)
  const float* y       = (const float*)d_in[1];  // (64, 8192, 3)
  const float* tnw     = (const float*)d_in[2];  // (64, 9356)
  float* out           = (float*)d_out;          // (64, 8192, 3)

  dim3 grid(NN / 512, BB, 1);  // 1024 blocks, 512 points each (2 supersteps x 256)
  dim3 block(512, 1, 1);
  ode_hypernet_kernel<<<grid, block, 0, stream>>>(context, y, tnw, out);
}